// Round 11
// baseline (439.258 us; speedup 1.0000x reference)
//
#include <hip/hip_runtime.h>
#include <math.h>

#define NOUT   10
#define ROWLEN 784           // 28*28
#define WTOT   (NOUT*ROWLEN) // 7840
#define BTHR   512
#define BROWS  128           // rows per block
#define TROWS  32            // rows per tile (512 thr, 4 rows/wave)
#define NTILE  (BROWS/TROWS) // 4

// ---------------------------------------------------------------------------
// Single fused kernel.
// Phase 1 (per block, ~2us, parallel everywhere): fold conv+quantum+linear
//   into Weff(10x784 fp32)+bias in LDS. lin_w is staged through a second LDS
//   buffer in two coalesced 31.4KB passes (fixes R3's scattered-load fold).
// Phase 2: stream 128 rows with R10's core (2 rows/thread, output-split
//   halves, depth-4 register prefetch).
// LDS 61.4KB -> 2 blocks/CU, 16 waves/CU.
// ---------------------------------------------------------------------------
__global__ __launch_bounds__(BTHR, 4)
void quanv_fused(const float* __restrict__ x,
                 const float* __restrict__ conv_w, // (4,1,2,2)
                 const float* __restrict__ conv_b, // (4,)
                 const float* __restrict__ q_w,    // (4,4) (out,in)
                 const float* __restrict__ lin_w,  // (10,1568)
                 const float* __restrict__ lin_b,  // (10,)
                 float* __restrict__ out)
{
    __shared__ float Wf[WTOT];     // 31360 B: folded Weff
    __shared__ float Lt[WTOT];     // 31360 B: lin_w staging (2 passes)
    __shared__ float bias[NOUT];
    __shared__ float rs[40];       // rowsum[o][c]

    const int t = threadIdx.x;

    // conv_w/q_w to registers (broadcast, L1-hot)
    float cw[16], qw[16];
    #pragma unroll
    for (int i = 0; i < 16; ++i) { cw[i] = conv_w[i]; qw[i] = q_w[i]; }

    // ---- Pass A: stage lin_w[:, 0:784] coalesced ----
    for (int idx = t; idx < WTOT; idx += BTHR) {
        const int o = idx / ROWLEN, u = idx - o * ROWLEN;
        Lt[idx] = lin_w[o * 1568 + u];
    }
    __syncthreads();

    // conv-part of Weff + bias rowsums (all from LDS)
    for (int idx = t; idx < WTOT; idx += BTHR) {
        const int o = idx / ROWLEN;
        const int j = idx - o * ROWLEN;
        const int h = j / 28, w = j - h * 28;
        const int p = (h >> 1) * 14 + (w >> 1);
        const int k = ((h & 1) << 1) | (w & 1);
        float s = 0.f;
        #pragma unroll
        for (int c = 0; c < 4; ++c)
            s += cw[c * 4 + k] * Lt[o * ROWLEN + c * 196 + p];
        Wf[idx] = s;
    }
    if (t < 320) {                 // 40 octets x 8 lanes
        const int oc = t >> 3, lane = t & 7;
        const int o = oc >> 2, c = oc & 3;
        float s = 0.f;
        #pragma unroll
        for (int p = 0; p < 196; p += 8) {
            const int pp = p + lane;
            if (pp < 196) s += Lt[o * ROWLEN + c * 196 + pp];
        }
        s += __shfl_xor(s, 1);
        s += __shfl_xor(s, 2);
        s += __shfl_xor(s, 4);
        if (lane == 0) rs[oc] = s;
    }
    __syncthreads();               // Lt free, rs ready

    // ---- Pass B: stage lin_w[:, 784:1568] coalesced ----
    for (int idx = t; idx < WTOT; idx += BTHR) {
        const int o = idx / ROWLEN, u = idx - o * ROWLEN;
        Lt[idx] = lin_w[o * 1568 + 784 + u];
    }
    __syncthreads();

    // quantum-part into Weff; bias
    for (int idx = t; idx < WTOT; idx += BTHR) {
        const int o = idx / ROWLEN;
        const int j = idx - o * ROWLEN;
        const int h = j / 28, w = j - h * 28;
        const int p = (h >> 1) * 14 + (w >> 1);
        const int k = ((h & 1) << 1) | (w & 1);
        float s = Wf[idx];
        #pragma unroll
        for (int q = 0; q < 4; ++q)
            s += qw[q * 4 + k] * Lt[o * ROWLEN + p * 4 + q];
        Wf[idx] = s;
    }
    if (t < NOUT) {
        float s = lin_b[t];
        #pragma unroll
        for (int c = 0; c < 4; ++c) s += conv_b[c] * rs[t * 4 + c];
        bias[t] = s;
    }
    __syncthreads();               // Weff + bias ready

    // ---- Phase 2: stream 128 rows (4 tiles of 32) ----
    const int lane = t & 63;
    const int wv   = t >> 6;           // wave 0..7
    const int l    = lane & 15;
    const int oh   = (lane >> 4) & 1;  // output half
    const int pr   = lane >> 5;        // row-pair in wave
    const int wb   = oh * 5 * ROWLEN;

    float bias_r[5];
    #pragma unroll
    for (int o = 0; o < 5; ++o) bias_r[o] = bias[oh * 5 + o];

    const size_t blockbase = (size_t)blockIdx.x * BROWS;

    for (int tile = 0; tile < NTILE; ++tile) {
        const int r0 = (int)blockbase + tile * TROWS + wv * 4 + pr * 2;
        const float* __restrict__ xr = x + (size_t)r0 * ROWLEN;

        // depth-4 prefetch prologue
        float4 px[4][2];
        #pragma unroll
        for (int j = 0; j < 4; ++j) {
            px[j][0] = *(const float4*)(xr + 4 * l + 64 * j);
            px[j][1] = *(const float4*)(xr + ROWLEN + 4 * l + 64 * j);
        }

        float acc[2][5];
        #pragma unroll
        for (int r = 0; r < 2; ++r)
            #pragma unroll
            for (int o = 0; o < 5; ++o) acc[r][o] = 0.f;

        #pragma unroll
        for (int i = 0; i < 12; ++i) {
            const int buf = i & 3;
            const float4 a0 = px[buf][0];
            const float4 a1 = px[buf][1];

            const int ni = i + 4;
            if (ni < 12) {
                const int nfo = 4 * l + 64 * ni;
                px[buf][0] = *(const float4*)(xr + nfo);
                px[buf][1] = *(const float4*)(xr + ROWLEN + nfo);
            } else if (ni == 12) {   // i==8 -> tail into px[0]
                const int tfo = 768 + 4 * (l & 3);
                px[0][0] = *(const float4*)(xr + tfo);
                px[0][1] = *(const float4*)(xr + ROWLEN + tfo);
            }

            const int fo = 4 * l + 64 * i;
            #pragma unroll
            for (int o = 0; o < 5; ++o) {
                const float4 w4 = *(const float4*)&Wf[wb + o * ROWLEN + fo];
                acc[0][o] = fmaf(a0.x, w4.x, fmaf(a0.y, w4.y,
                            fmaf(a0.z, w4.z, fmaf(a0.w, w4.w, acc[0][o]))));
                acc[1][o] = fmaf(a1.x, w4.x, fmaf(a1.y, w4.y,
                            fmaf(a1.z, w4.z, fmaf(a1.w, w4.w, acc[1][o]))));
            }
        }
        if (l < 4) {                 // tail floats 768..783 (in px[0])
            const int fo = 768 + 4 * l;
            #pragma unroll
            for (int o = 0; o < 5; ++o) {
                const float4 w4 = *(const float4*)&Wf[wb + o * ROWLEN + fo];
                acc[0][o] = fmaf(px[0][0].x, w4.x, fmaf(px[0][0].y, w4.y,
                            fmaf(px[0][0].z, w4.z, fmaf(px[0][0].w, w4.w, acc[0][o]))));
                acc[1][o] = fmaf(px[0][1].x, w4.x, fmaf(px[0][1].y, w4.y,
                            fmaf(px[0][1].z, w4.z, fmaf(px[0][1].w, w4.w, acc[1][o]))));
            }
        }

        // 16-lane butterfly
        #pragma unroll
        for (int r = 0; r < 2; ++r)
            #pragma unroll
            for (int o = 0; o < 5; ++o) {
                acc[r][o] += __shfl_xor(acc[r][o], 1);
                acc[r][o] += __shfl_xor(acc[r][o], 2);
                acc[r][o] += __shfl_xor(acc[r][o], 4);
                acc[r][o] += __shfl_xor(acc[r][o], 8);
            }

        // bias + output-half exchange
        float own[2][5], ex[2][5];
        #pragma unroll
        for (int r = 0; r < 2; ++r)
            #pragma unroll
            for (int o = 0; o < 5; ++o) {
                own[r][o] = acc[r][o] + bias_r[o];
                ex[r][o]  = __shfl_xor(own[r][o], 16);
            }

        float lg[NOUT];
        #pragma unroll
        for (int o = 0; o < 5; ++o) {
            lg[o]     = oh ? ex[1][o]  : own[0][o];
            lg[o + 5] = oh ? own[1][o] : ex[0][o];
        }

        float m = -1e30f;
        #pragma unroll
        for (int o = 0; o < NOUT; ++o) m = fmaxf(m, lg[o]);
        float s = 0.f;
        #pragma unroll
        for (int o = 0; o < NOUT; ++o) s += expf(lg[o] - m);
        const float lse = m + logf(s);

        if (l < NOUT) {
            float v = lg[0];
            #pragma unroll
            for (int o = 1; o < NOUT; ++o) v = (l == o) ? lg[o] : v;
            out[(size_t)(r0 + oh) * NOUT + l] = v - lse;
        }
    }
}

extern "C" void kernel_launch(void* const* d_in, const int* in_sizes, int n_in,
                              void* d_out, int out_size, void* d_ws, size_t ws_size,
                              hipStream_t stream) {
    const float* x      = (const float*)d_in[0];
    const float* conv_w = (const float*)d_in[1];
    const float* conv_b = (const float*)d_in[2];
    const float* q_w    = (const float*)d_in[3];
    const float* lin_w  = (const float*)d_in[4];
    const float* lin_b  = (const float*)d_in[5];
    float* out = (float*)d_out;

    const int rows = in_sizes[0] / ROWLEN;   // 32768
    quanv_fused<<<rows / BROWS, BTHR, 0, stream>>>(x, conv_w, conv_b, q_w,
                                                   lin_w, lin_b, out);
}

// Round 12
// 67.386 us; speedup vs baseline: 6.5185x; 6.5185x over previous
//
#include <hip/hip_runtime.h>
#include <math.h>

#define NOUT   10
#define ROWLEN 784           // 28*28
#define WTOT   (NOUT*ROWLEN) // 7840
#define BTHR   512
#define BROWS  64            // rows per block
#define TROWS  32            // rows per tile (8 waves x 4 rows)
#define NTILE  (BROWS/TROWS) // 2

// ---------------------------------------------------------------------------
// Single fused kernel.
// Phase 1: fold conv+quantum+linear into Weff(10x784 fp32)+bias in LDS.
//   lin_w staged through a second LDS buffer in two coalesced 31.4KB passes.
// Phase 2: stream 64 rows with the R10 core (2 rows/thread, output-split
//   halves, depth-4 register prefetch).
// LDS 61.4KB -> 2 blocks/CU, 16 waves/CU. grid 512 = 2 blocks/CU.
// NOTE: no min-waves arg in __launch_bounds__ — R6/R11 both died to the
// compiler's pessimistic VGPR cap (spills at 3 TB/s). Natural alloc only.
// ---------------------------------------------------------------------------
__global__ __launch_bounds__(BTHR)
void quanv_fused(const float* __restrict__ x,
                 const float* __restrict__ conv_w, // (4,1,2,2)
                 const float* __restrict__ conv_b, // (4,)
                 const float* __restrict__ q_w,    // (4,4) (out,in)
                 const float* __restrict__ lin_w,  // (10,1568)
                 const float* __restrict__ lin_b,  // (10,)
                 float* __restrict__ out)
{
    __shared__ float Wf[WTOT];     // 31360 B: folded Weff
    __shared__ float Lt[WTOT];     // 31360 B: lin_w staging (2 passes)
    __shared__ float bias[NOUT];
    __shared__ float rs[40];       // rowsum[o][c]

    const int t = threadIdx.x;

    // conv_w/q_w to registers (broadcast, L1-hot)
    float cw[16], qw[16];
    #pragma unroll
    for (int i = 0; i < 16; ++i) { cw[i] = conv_w[i]; qw[i] = q_w[i]; }

    // ---- Pass A: stage lin_w[:, 0:784] coalesced ----
    for (int idx = t; idx < WTOT; idx += BTHR) {
        const int o = idx / ROWLEN, u = idx - o * ROWLEN;
        Lt[idx] = lin_w[o * 1568 + u];
    }
    __syncthreads();

    // conv-part of Weff + bias rowsums (all from LDS)
    for (int idx = t; idx < WTOT; idx += BTHR) {
        const int o = idx / ROWLEN;
        const int j = idx - o * ROWLEN;
        const int h = j / 28, w = j - h * 28;
        const int p = (h >> 1) * 14 + (w >> 1);
        const int k = ((h & 1) << 1) | (w & 1);
        float s = 0.f;
        #pragma unroll
        for (int c = 0; c < 4; ++c)
            s += cw[c * 4 + k] * Lt[o * ROWLEN + c * 196 + p];
        Wf[idx] = s;
    }
    if (t < 320) {                 // 40 octets x 8 lanes
        const int oc = t >> 3, lane = t & 7;
        const int o = oc >> 2, c = oc & 3;
        float s = 0.f;
        #pragma unroll
        for (int p = 0; p < 196; p += 8) {
            const int pp = p + lane;
            if (pp < 196) s += Lt[o * ROWLEN + c * 196 + pp];
        }
        s += __shfl_xor(s, 1);
        s += __shfl_xor(s, 2);
        s += __shfl_xor(s, 4);
        if (lane == 0) rs[oc] = s;
    }
    __syncthreads();               // Lt reads done, rs ready

    // ---- Pass B: stage lin_w[:, 784:1568] coalesced ----
    for (int idx = t; idx < WTOT; idx += BTHR) {
        const int o = idx / ROWLEN, u = idx - o * ROWLEN;
        Lt[idx] = lin_w[o * 1568 + 784 + u];
    }
    __syncthreads();

    // quantum-part into Weff; bias
    for (int idx = t; idx < WTOT; idx += BTHR) {
        const int o = idx / ROWLEN;
        const int j = idx - o * ROWLEN;
        const int h = j / 28, w = j - h * 28;
        const int p = (h >> 1) * 14 + (w >> 1);
        const int k = ((h & 1) << 1) | (w & 1);
        float s = Wf[idx];
        #pragma unroll
        for (int q = 0; q < 4; ++q)
            s += qw[q * 4 + k] * Lt[o * ROWLEN + p * 4 + q];
        Wf[idx] = s;
    }
    if (t < NOUT) {
        float s = lin_b[t];
        #pragma unroll
        for (int c = 0; c < 4; ++c) s += conv_b[c] * rs[t * 4 + c];
        bias[t] = s;
    }
    __syncthreads();               // Weff + bias ready

    // ---- Phase 2: stream 64 rows (2 tiles of 32) ----
    const int lane = t & 63;
    const int wv   = t >> 6;           // wave 0..7
    const int l    = lane & 15;
    const int oh   = (lane >> 4) & 1;  // output half
    const int pr   = lane >> 5;        // row-pair in wave
    const int wb   = oh * 5 * ROWLEN;

    float bias_r[5];
    #pragma unroll
    for (int o = 0; o < 5; ++o) bias_r[o] = bias[oh * 5 + o];

    const size_t blockbase = (size_t)blockIdx.x * BROWS;

    #pragma unroll
    for (int tile = 0; tile < NTILE; ++tile) {
        const int r0 = (int)blockbase + tile * TROWS + wv * 4 + pr * 2;
        const float* __restrict__ xr = x + (size_t)r0 * ROWLEN;

        // depth-4 prefetch prologue
        float4 px[4][2];
        #pragma unroll
        for (int j = 0; j < 4; ++j) {
            px[j][0] = *(const float4*)(xr + 4 * l + 64 * j);
            px[j][1] = *(const float4*)(xr + ROWLEN + 4 * l + 64 * j);
        }

        float acc[2][5];
        #pragma unroll
        for (int r = 0; r < 2; ++r)
            #pragma unroll
            for (int o = 0; o < 5; ++o) acc[r][o] = 0.f;

        #pragma unroll
        for (int i = 0; i < 12; ++i) {
            const int buf = i & 3;
            const float4 a0 = px[buf][0];
            const float4 a1 = px[buf][1];

            const int ni = i + 4;
            if (ni < 12) {
                const int nfo = 4 * l + 64 * ni;
                px[buf][0] = *(const float4*)(xr + nfo);
                px[buf][1] = *(const float4*)(xr + ROWLEN + nfo);
            } else if (ni == 12) {   // i==8 -> tail into px[0]
                const int tfo = 768 + 4 * (l & 3);
                px[0][0] = *(const float4*)(xr + tfo);
                px[0][1] = *(const float4*)(xr + ROWLEN + tfo);
            }

            const int fo = 4 * l + 64 * i;
            #pragma unroll
            for (int o = 0; o < 5; ++o) {
                const float4 w4 = *(const float4*)&Wf[wb + o * ROWLEN + fo];
                acc[0][o] = fmaf(a0.x, w4.x, fmaf(a0.y, w4.y,
                            fmaf(a0.z, w4.z, fmaf(a0.w, w4.w, acc[0][o]))));
                acc[1][o] = fmaf(a1.x, w4.x, fmaf(a1.y, w4.y,
                            fmaf(a1.z, w4.z, fmaf(a1.w, w4.w, acc[1][o]))));
            }
        }
        if (l < 4) {                 // tail floats 768..783 (in px[0])
            const int fo = 768 + 4 * l;
            #pragma unroll
            for (int o = 0; o < 5; ++o) {
                const float4 w4 = *(const float4*)&Wf[wb + o * ROWLEN + fo];
                acc[0][o] = fmaf(px[0][0].x, w4.x, fmaf(px[0][0].y, w4.y,
                            fmaf(px[0][0].z, w4.z, fmaf(px[0][0].w, w4.w, acc[0][o]))));
                acc[1][o] = fmaf(px[0][1].x, w4.x, fmaf(px[0][1].y, w4.y,
                            fmaf(px[0][1].z, w4.z, fmaf(px[0][1].w, w4.w, acc[1][o]))));
            }
        }

        // 16-lane butterfly
        #pragma unroll
        for (int r = 0; r < 2; ++r)
            #pragma unroll
            for (int o = 0; o < 5; ++o) {
                acc[r][o] += __shfl_xor(acc[r][o], 1);
                acc[r][o] += __shfl_xor(acc[r][o], 2);
                acc[r][o] += __shfl_xor(acc[r][o], 4);
                acc[r][o] += __shfl_xor(acc[r][o], 8);
            }

        // bias + output-half exchange
        float own[2][5], ex[2][5];
        #pragma unroll
        for (int r = 0; r < 2; ++r)
            #pragma unroll
            for (int o = 0; o < 5; ++o) {
                own[r][o] = acc[r][o] + bias_r[o];
                ex[r][o]  = __shfl_xor(own[r][o], 16);
            }

        float lg[NOUT];
        #pragma unroll
        for (int o = 0; o < 5; ++o) {
            lg[o]     = oh ? ex[1][o]  : own[0][o];
            lg[o + 5] = oh ? own[1][o] : ex[0][o];
        }

        float m = -1e30f;
        #pragma unroll
        for (int o = 0; o < NOUT; ++o) m = fmaxf(m, lg[o]);
        float s = 0.f;
        #pragma unroll
        for (int o = 0; o < NOUT; ++o) s += expf(lg[o] - m);
        const float lse = m + logf(s);

        if (l < NOUT) {
            float v = lg[0];
            #pragma unroll
            for (int o = 1; o < NOUT; ++o) v = (l == o) ? lg[o] : v;
            out[(size_t)(r0 + oh) * NOUT + l] = v - lse;
        }
    }
}

extern "C" void kernel_launch(void* const* d_in, const int* in_sizes, int n_in,
                              void* d_out, int out_size, void* d_ws, size_t ws_size,
                              hipStream_t stream) {
    const float* x      = (const float*)d_in[0];
    const float* conv_w = (const float*)d_in[1];
    const float* conv_b = (const float*)d_in[2];
    const float* q_w    = (const float*)d_in[3];
    const float* lin_w  = (const float*)d_in[4];
    const float* lin_b  = (const float*)d_in[5];
    float* out = (float*)d_out;

    const int rows = in_sizes[0] / ROWLEN;   // 32768
    quanv_fused<<<rows / BROWS, BTHR, 0, stream>>>(x, conv_w, conv_b, q_w,
                                                   lin_w, lin_b, out);
}

// Round 13
// 32.158 us; speedup vs baseline: 13.6594x; 2.0955x over previous
//
#include <hip/hip_runtime.h>
#include <math.h>

#define NOUT   10
#define ROWLEN 784           // 28*28
#define WTOT   (NOUT*ROWLEN) // 7840
#define TROWS  32            // rows per tile (R5 core)
#define NTILE  2
#define BROWS  (TROWS*NTILE) // 64 rows per block

// ws layout: [7840 float W][10 float bias]

// ---------------------------------------------------------------------------
// Prep: fold conv+quantum+linear into Weff (10x784 fp32) + bias, into d_ws.
// ---------------------------------------------------------------------------
__global__ __launch_bounds__(256)
void quanv_prep(const float* __restrict__ conv_w, // (4,1,2,2)
                const float* __restrict__ conv_b, // (4,)
                const float* __restrict__ q_w,    // (4,4) (out,in)
                const float* __restrict__ lin_w,  // (10,1568)
                const float* __restrict__ lin_b,  // (10,)
                float* __restrict__ W)            // ws: [7840 W][10 bias]
{
    const int t = threadIdx.x;

    for (int idx = blockIdx.x * 256 + t; idx < WTOT; idx += gridDim.x * 256) {
        const int o = idx / ROWLEN;
        const int j = idx - o * ROWLEN;          // pixel h*28+w
        const int h = j / 28, w = j - h * 28;
        const int p = (h >> 1) * 14 + (w >> 1);  // patch index (196)
        const int k = (h & 1) * 2 + (w & 1);     // pos in 2x2 patch
        float s = 0.f;
        #pragma unroll
        for (int c = 0; c < 4; ++c)              // conv branch
            s += conv_w[c * 4 + k] * lin_w[o * 1568 + c * 196 + p];
        #pragma unroll
        for (int q = 0; q < 4; ++q)              // quantum branch
            s += q_w[q * 4 + k] * lin_w[o * 1568 + 784 + p * 4 + q];
        W[idx] = s;
    }

    if (blockIdx.x == 0) {
        __shared__ float rs[40];                 // rowsum[o][c]
        const int lane = t & 7;
        for (int pair = t >> 3; pair < 40; pair += 32) {
            const int o = pair >> 2, c = pair & 3;
            const float* base = lin_w + o * 1568 + c * 196;
            float s = 0.f;
            #pragma unroll
            for (int p = 0; p < 196; p += 8) {
                const int pp = p + lane;
                if (pp < 196) s += base[pp];
            }
            s += __shfl_xor(s, 1);
            s += __shfl_xor(s, 2);
            s += __shfl_xor(s, 4);
            if (lane == 0) rs[pair] = s;
        }
        __syncthreads();
        if (t < NOUT) {
            float s = lin_b[t];
            #pragma unroll
            for (int c = 0; c < 4; ++c) s += conv_b[c] * rs[t * 4 + c];
            W[WTOT + t] = s;
        }
    }
}

// ---------------------------------------------------------------------------
// Main = R5 core (best, 31.9us) with the block prologue amortized over
// 2 tiles (64 rows/block, grid 512): W-fill count 2048 -> 512.
// Layout per tile: 32-lane pair owns 4 adjacent rows; lower 16 lanes
// accumulate outputs 0..4, upper 16 outputs 5..9. Depth-2 prefetch.
// No min-waves clause (R6/R11 lesson: forced VGPR caps -> spill disaster).
// ---------------------------------------------------------------------------
__global__ __launch_bounds__(256)
void quanv_main(const float* __restrict__ x,
                const float* __restrict__ Wg,   // ws
                float* __restrict__ out)
{
    __shared__ float Wl[WTOT];
    __shared__ float bias[NOUT];

    const int t     = threadIdx.x;
    const int lane  = t & 63;
    const int wv    = t >> 6;          // wave in block
    const int l     = lane & 15;       // lane in 16-group
    const int grp   = lane >> 4;       // 0..3
    const int pair  = grp >> 1;        // 0,1
    const int gp    = grp & 1;         // output-half selector
    const int obase = gp * 5;
    const int wb    = obase * ROWLEN;

    const size_t blockbase = (size_t)blockIdx.x * BROWS;

    // first tile's x prefetch issued BEFORE the LDS fill (independent work)
    const int rA = (int)blockbase + wv * 8 + pair * 4;
    const float* __restrict__ xrA = x + (size_t)rA * ROWLEN;

    float4 px0[4], px1[4];
    #pragma unroll
    for (int r = 0; r < 4; ++r) {
        px0[r] = *(const float4*)(xrA + r * ROWLEN + 4 * l);
        px1[r] = *(const float4*)(xrA + r * ROWLEN + 4 * l + 64);
    }

    {   // coalesced LDS fill: 1960 float4 over 256 threads (once per block)
        const float4* __restrict__ src = (const float4*)Wg;
        float4* dst = (float4*)Wl;
        #pragma unroll
        for (int i = 0; i < 8; ++i) {
            const int idx = t + 256 * i;
            if (idx < WTOT / 4) dst[idx] = src[idx];
        }
        if (t < NOUT) bias[t] = Wg[WTOT + t];
    }
    __syncthreads();

    float bias_r[5];
    #pragma unroll
    for (int o = 0; o < 5; ++o) bias_r[o] = bias[obase + o];

    #pragma unroll
    for (int tile = 0; tile < NTILE; ++tile) {
        const int r0 = (int)blockbase + tile * TROWS + wv * 8 + pair * 4;
        const float* __restrict__ xr = x + (size_t)r0 * ROWLEN;

        if (tile > 0) {   // prologue prefetch for tiles after the first
            #pragma unroll
            for (int r = 0; r < 4; ++r) {
                px0[r] = *(const float4*)(xr + r * ROWLEN + 4 * l);
                px1[r] = *(const float4*)(xr + r * ROWLEN + 4 * l + 64);
            }
        }

        float acc[4][5];
        #pragma unroll
        for (int r = 0; r < 4; ++r)
            #pragma unroll
            for (int o = 0; o < 5; ++o) acc[r][o] = 0.f;

        #pragma unroll
        for (int i = 0; i < 12; ++i) {
            float4 cur[4];
            #pragma unroll
            for (int r = 0; r < 4; ++r) cur[r] = ((i & 1) == 0) ? px0[r] : px1[r];

            const int ni = i + 2;                    // depth-2 prefetch
            if (ni < 12) {
                const int nfo = 4 * l + 64 * ni;
                #pragma unroll
                for (int r = 0; r < 4; ++r) {
                    const float4 v = *(const float4*)(xr + r * ROWLEN + nfo);
                    if ((i & 1) == 0) px0[r] = v; else px1[r] = v;
                }
            } else if (ni == 12) {                   // i==10 -> tail into px0
                const int tfo = 768 + 4 * (l & 3);
                #pragma unroll
                for (int r = 0; r < 4; ++r)
                    px0[r] = *(const float4*)(xr + r * ROWLEN + tfo);
            }

            const int fo = 4 * l + 64 * i;
            #pragma unroll
            for (int o = 0; o < 5; ++o) {
                const float4 w4 = *(const float4*)&Wl[wb + o * ROWLEN + fo];
                #pragma unroll
                for (int r = 0; r < 4; ++r)
                    acc[r][o] = fmaf(cur[r].x, w4.x, fmaf(cur[r].y, w4.y,
                                fmaf(cur[r].z, w4.z, fmaf(cur[r].w, w4.w, acc[r][o]))));
            }
        }
        // tail: floats 768..783 (in px0, loaded at i==10); lanes 0..3 only
        if (l < 4) {
            const int fo = 768 + 4 * l;
            #pragma unroll
            for (int o = 0; o < 5; ++o) {
                const float4 w4 = *(const float4*)&Wl[wb + o * ROWLEN + fo];
                #pragma unroll
                for (int r = 0; r < 4; ++r)
                    acc[r][o] = fmaf(px0[r].x, w4.x, fmaf(px0[r].y, w4.y,
                                fmaf(px0[r].z, w4.z, fmaf(px0[r].w, w4.w, acc[r][o]))));
            }
        }

        // butterfly over the 16-lane group
        #pragma unroll
        for (int r = 0; r < 4; ++r)
            #pragma unroll
            for (int o = 0; o < 5; ++o) {
                acc[r][o] += __shfl_xor(acc[r][o], 1);
                acc[r][o] += __shfl_xor(acc[r][o], 2);
                acc[r][o] += __shfl_xor(acc[r][o], 4);
                acc[r][o] += __shfl_xor(acc[r][o], 8);
            }

        // add own-half bias, exchange with the partner half (xor 16)
        float own[4][5], part[4][5];
        #pragma unroll
        for (int r = 0; r < 4; ++r)
            #pragma unroll
            for (int o = 0; o < 5; ++o) {
                own[r][o]  = acc[r][o] + bias_r[o];
                part[r][o] = __shfl_xor(own[r][o], 16);
            }

        // this lane finishes rows (2*gp, 2*gp+1) of its pair
        float lgA[10], lgB[10];
        #pragma unroll
        for (int o = 0; o < 5; ++o) {
            lgA[o]     = gp ? part[2][o] : own[0][o];
            lgA[o + 5] = gp ? own[2][o]  : part[0][o];
            lgB[o]     = gp ? part[3][o] : own[1][o];
            lgB[o + 5] = gp ? own[3][o]  : part[1][o];
        }

        float mA = -1e30f, mB = -1e30f;
        #pragma unroll
        for (int o = 0; o < 10; ++o) { mA = fmaxf(mA, lgA[o]); mB = fmaxf(mB, lgB[o]); }
        float sA = 0.f, sB = 0.f;
        #pragma unroll
        for (int o = 0; o < 10; ++o) { sA += expf(lgA[o] - mA); sB += expf(lgB[o] - mB); }
        const float lseA = mA + logf(sA);
        const float lseB = mB + logf(sB);

        if (l < NOUT) {
            float vA = lgA[0], vB = lgB[0];
            #pragma unroll
            for (int o = 1; o < 10; ++o) {
                vA = (l == o) ? lgA[o] : vA;
                vB = (l == o) ? lgB[o] : vB;
            }
            const int rw = r0 + 2 * gp;
            out[(size_t)rw * NOUT + l]       = vA - lseA;
            out[(size_t)(rw + 1) * NOUT + l] = vB - lseB;
        }
    }
}

extern "C" void kernel_launch(void* const* d_in, const int* in_sizes, int n_in,
                              void* d_out, int out_size, void* d_ws, size_t ws_size,
                              hipStream_t stream) {
    const float* x      = (const float*)d_in[0];
    const float* conv_w = (const float*)d_in[1];
    const float* conv_b = (const float*)d_in[2];
    const float* q_w    = (const float*)d_in[3];
    const float* lin_w  = (const float*)d_in[4];
    const float* lin_b  = (const float*)d_in[5];
    float* out = (float*)d_out;
    float* W   = (float*)d_ws;   // 7850 floats

    const int rows = in_sizes[0] / ROWLEN;   // 32768

    quanv_prep<<<31, 256, 0, stream>>>(conv_w, conv_b, q_w, lin_w, lin_b, W);
    quanv_main<<<rows / BROWS, 256, 0, stream>>>(x, W, out);
}